// Round 9
// baseline (323.823 us; speedup 1.0000x reference)
//
#include <hip/hip_runtime.h>
#include <hip/hip_bf16.h>
#include <hip/hip_cooperative_groups.h>
#include <stdint.h>

namespace cg = cooperative_groups;

// TopKPooling (haiku-geometric): N=200000, C=256, B=64, E=3.2M, RATIO=0.5
// Inputs (f32/int32): x [N,C] f32, p [C] f32, senders/receivers int32, batch int32 (sorted).
// Output d_out: FLOAT32, concatenated (x_out [N*C] | senders_out [E] | receivers_out [E]
// | new_batch_sorted [N]).
//
// R9: single cooperative kernel, 3 phases split by grid.sync():
//   P1 scores+boundary (ILP-2 rows/wave, grid-stride)
//   P2 per-graph stats (blocks 0..63) + prefix scan (block 64)
//   P3 scatter (ILP-2, normal x loads: L3-resident; nt stores) then edges drain.
// Removes 3 launch gaps and overlaps the edge stream with the scatter tail.

#define RATIO 0.5f

typedef float f32x4 __attribute__((ext_vector_type(4)));
typedef int   i32x4 __attribute__((ext_vector_type(4)));

__global__ __launch_bounds__(256) void mega(
    const float* __restrict__ x, const float* __restrict__ p,
    const int* __restrict__ snd, const int* __restrict__ rcv,
    const int* __restrict__ batch,
    float* __restrict__ s, int* __restrict__ start,
    int* __restrict__ kk, int* __restrict__ Kb, int* __restrict__ Db,
    int* __restrict__ Ktot, float* __restrict__ mx, float* __restrict__ denom,
    float* __restrict__ xout, float* __restrict__ nbout,
    float* __restrict__ sout, float* __restrict__ rout,
    int N, int B, int E) {
    cg::grid_group grid = cg::this_grid();
    const int lane = threadIdx.x & 63;
    const int wid = blockIdx.x * (blockDim.x >> 6) + (threadIdx.x >> 6);
    const int nwaves = gridDim.x * (blockDim.x >> 6);
    const int npairs = N >> 1;                    // N even

    // ---- Phase 1: scores + boundary ----
    {
        const f32x4 pv = *reinterpret_cast<const f32x4*>(p + lane * 4);
        for (int pr = wid; pr < npairs; pr += nwaves) {
            int node0 = pr * 2, node1 = node0 + 1;
            const f32x4 a = *reinterpret_cast<const f32x4*>(x + (size_t)node0 * 256 + lane * 4);
            const f32x4 b = *reinterpret_cast<const f32x4*>(x + (size_t)node1 * 256 + lane * 4);
            float acc0 = a.x * pv.x + a.y * pv.y + a.z * pv.z + a.w * pv.w;
            float acc1 = b.x * pv.x + b.y * pv.y + b.z * pv.z + b.w * pv.w;
            #pragma unroll
            for (int off = 32; off; off >>= 1) {
                acc0 += __shfl_down(acc0, off, 64);
                acc1 += __shfl_down(acc1, off, 64);
            }
            if (lane == 0) {
                s[node0] = acc0;
                s[node1] = acc1;
                int b0 = batch[node0];
                if (node0 == 0 || batch[node0 - 1] != b0) start[b0] = node0;
                int b1 = batch[node1];
                if (b0 != b1) start[b1] = node1;
            }
        }
    }
    grid.sync();

    // ---- Phase 2: per-graph stats + prefix scan ----
    if (blockIdx.x < (unsigned)B) {
        int g = blockIdx.x;
        int st = start[g];
        int en = (g == B - 1) ? N : start[g + 1];
        __shared__ float red[256];
        float m = -INFINITY;
        for (int i = st + threadIdx.x; i < en; i += 256) m = fmaxf(m, s[i]);
        red[threadIdx.x] = m; __syncthreads();
        for (int o = 128; o; o >>= 1) {
            if (threadIdx.x < o) red[threadIdx.x] = fmaxf(red[threadIdx.x], red[threadIdx.x + o]);
            __syncthreads();
        }
        m = red[0]; __syncthreads();
        float sum = 0.f;
        for (int i = st + threadIdx.x; i < en; i += 256) sum += expf(s[i] - m);
        red[threadIdx.x] = sum; __syncthreads();
        for (int o = 128; o; o >>= 1) {
            if (threadIdx.x < o) red[threadIdx.x] += red[threadIdx.x + o];
            __syncthreads();
        }
        if (threadIdx.x == 0) { mx[g] = m; denom[g] = red[0]; }
    } else if (blockIdx.x == (unsigned)B && threadIdx.x < 64) {
        int g = threadIdx.x;
        int st = start[g];
        int en = (g == B - 1) ? N : start[g + 1];
        int cnt = en - st;
        int kv = (int)ceilf(RATIO * (float)cnt);
        int dv = cnt - kv;
        int kp = kv, dp = dv;
        #pragma unroll
        for (int off = 1; off < 64; off <<= 1) {
            int a = __shfl_up(kp, off, 64);
            int b_ = __shfl_up(dp, off, 64);
            if (g >= off) { kp += a; dp += b_; }
        }
        kk[g] = kv;
        Kb[g] = kp - kv;
        Db[g] = dp - dv;
        if (g == B - 1) *Ktot = kp;
    }
    grid.sync();

    // ---- Phase 3: scatter (ILP-2) then edges drain ----
    const int kt = *Ktot;
    for (int pr = wid; pr < npairs; pr += nwaves) {
        int node0 = pr * 2, node1 = node0 + 1;
        int g0 = batch[node0], g1 = batch[node1];
        int idx0 = node0 - start[g0], idx1 = node1 - start[g1];
        int kv0 = kk[g0], kv1 = kk[g1];
        bool kept0 = idx0 < kv0, kept1 = idx1 < kv1;
        int pos0 = kept0 ? (Kb[g0] + idx0) : (kt + Db[g0] + (idx0 - kv0));
        int pos1 = kept1 ? (Kb[g1] + idx1) : (kt + Db[g1] + (idx1 - kv1));
        float sc0 = expf(s[node0] - mx[g0]) / denom[g0];
        float sc1 = expf(s[node1] - mx[g1]) / denom[g1];
        const f32x4 a = *reinterpret_cast<const f32x4*>(x + (size_t)node0 * 256 + lane * 4);
        const f32x4 b = *reinterpret_cast<const f32x4*>(x + (size_t)node1 * 256 + lane * 4);
        f32x4 oa, ob;
        oa.x = a.x * sc0; oa.y = a.y * sc0; oa.z = a.z * sc0; oa.w = a.w * sc0;
        ob.x = b.x * sc1; ob.y = b.y * sc1; ob.z = b.z * sc1; ob.w = b.w * sc1;
        __builtin_nontemporal_store(oa, reinterpret_cast<f32x4*>(xout + (size_t)pos0 * 256 + lane * 4));
        __builtin_nontemporal_store(ob, reinterpret_cast<f32x4*>(xout + (size_t)pos1 * 256 + lane * 4));
        if (lane == 0) {
            __builtin_nontemporal_store((float)(kept0 ? g0 : B), nbout + pos0);
            __builtin_nontemporal_store((float)(kept1 ? g1 : B), nbout + pos1);
        }
    }
    // edges: 8 per thread, grid-stride
    {
        int tid = blockIdx.x * blockDim.x + threadIdx.x;
        int nthr = gridDim.x * blockDim.x;
        int nchunks = (E + 7) / 8;
        for (int c = tid; c < nchunks; c += nthr) {
            long base = (long)c * 8;
            if (base + 8 <= E) {
                i32x4 s0 = __builtin_nontemporal_load(reinterpret_cast<const i32x4*>(snd + base));
                i32x4 s1 = __builtin_nontemporal_load(reinterpret_cast<const i32x4*>(snd + base + 4));
                i32x4 r0 = __builtin_nontemporal_load(reinterpret_cast<const i32x4*>(rcv + base));
                i32x4 r1 = __builtin_nontemporal_load(reinterpret_cast<const i32x4*>(rcv + base + 4));
                f32x4 so0, so1, ro0, ro1;
                so0.x = (float)(((s0.x >= kt) || (r0.x >= kt)) ? r0.x : s0.x);
                so0.y = (float)(((s0.y >= kt) || (r0.y >= kt)) ? r0.y : s0.y);
                so0.z = (float)(((s0.z >= kt) || (r0.z >= kt)) ? r0.z : s0.z);
                so0.w = (float)(((s0.w >= kt) || (r0.w >= kt)) ? r0.w : s0.w);
                so1.x = (float)(((s1.x >= kt) || (r1.x >= kt)) ? r1.x : s1.x);
                so1.y = (float)(((s1.y >= kt) || (r1.y >= kt)) ? r1.y : s1.y);
                so1.z = (float)(((s1.z >= kt) || (r1.z >= kt)) ? r1.z : s1.z);
                so1.w = (float)(((s1.w >= kt) || (r1.w >= kt)) ? r1.w : s1.w);
                ro0.x = (float)r0.x; ro0.y = (float)r0.y; ro0.z = (float)r0.z; ro0.w = (float)r0.w;
                ro1.x = (float)r1.x; ro1.y = (float)r1.y; ro1.z = (float)r1.z; ro1.w = (float)r1.w;
                __builtin_nontemporal_store(so0, reinterpret_cast<f32x4*>(sout + base));
                __builtin_nontemporal_store(so1, reinterpret_cast<f32x4*>(sout + base + 4));
                __builtin_nontemporal_store(ro0, reinterpret_cast<f32x4*>(rout + base));
                __builtin_nontemporal_store(ro1, reinterpret_cast<f32x4*>(rout + base + 4));
            } else {
                for (long e = base; e < E; ++e) {
                    int sv = snd[e], rv = rcv[e];
                    bool m = (sv >= kt) || (rv >= kt);
                    sout[e] = (float)(m ? rv : sv);
                    rout[e] = (float)rv;
                }
            }
        }
    }
}

extern "C" void kernel_launch(void* const* d_in, const int* in_sizes, int n_in,
                              void* d_out, int out_size, void* d_ws, size_t ws_size,
                              hipStream_t stream) {
    const float* x = (const float*)d_in[0];
    const float* p = (const float*)d_in[1];
    const int* senders = (const int*)d_in[2];
    const int* receivers = (const int*)d_in[3];
    const int* batch = (const int*)d_in[4];

    const int C = in_sizes[1];   // 256
    int E = in_sizes[2];         // 3,200,000
    int N = in_sizes[4];         // 200,000
    int B = 64;

    char* ws = (char*)d_ws;
    float* s   = (float*)ws;                       // N floats
    int* start = (int*)(ws + (size_t)N * 4);       // B ints
    int* kk    = start + B;
    int* Kb    = kk + B;
    int* Db    = Kb + B;
    int* Ktot  = Db + B;
    float* mx    = (float*)(Ktot + 1);
    float* denom = mx + B;

    float* out   = (float*)d_out;
    float* xout  = out;
    float* sout  = out + (size_t)N * C;
    float* rout  = sout + E;
    float* nbout = rout + E;

    void* args[] = {
        (void*)&x, (void*)&p, (void*)&senders, (void*)&receivers, (void*)&batch,
        (void*)&s, (void*)&start, (void*)&kk, (void*)&Kb, (void*)&Db,
        (void*)&Ktot, (void*)&mx, (void*)&denom,
        (void*)&xout, (void*)&nbout, (void*)&sout, (void*)&rout,
        (void*)&N, (void*)&B, (void*)&E
    };
    hipLaunchCooperativeKernel((const void*)mega, dim3(1024), dim3(256),
                               args, 0, stream);
}

// Round 10
// 114.131 us; speedup vs baseline: 2.8373x; 2.8373x over previous
//
#include <hip/hip_runtime.h>
#include <hip/hip_bf16.h>
#include <stdint.h>

// TopKPooling (haiku-geometric): N=200000, C=256, B=64, E=3.2M, RATIO=0.5
// Inputs (f32/int32): x [N,C] f32, p [C] f32, senders/receivers int32, batch int32 (sorted).
// Output d_out: FLOAT32, concatenated (x_out [N*C] | senders_out [E] | receivers_out [E]
// | new_batch_sorted [N]).
//
// R10: revert R9's cooperative kernel (grid.sync too costly: 324 µs). Back to R8
// (114.8 µs) + ONE change: merge k4_edges into k3 by block-granular partition
// (edge blocks appended to the scatter grid; wave-uniform branch, no divergence)
// so the edge stream overlaps scatter and one launch gap disappears.

#define RATIO 0.5f

typedef float f32x4 __attribute__((ext_vector_type(4)));
typedef int   i32x4 __attribute__((ext_vector_type(4)));

// Kernel 1: scores (2 rows per wave, float4 per lane, C=256) + boundary detection.
__global__ __launch_bounds__(256) void k1_scores_boundary(
    const float* __restrict__ x, const float* __restrict__ p,
    const int* __restrict__ batch,
    float* __restrict__ s, int* __restrict__ start, int N) {
    int node0 = blockIdx.x * 8 + (threadIdx.x >> 6) * 2;
    int lane = threadIdx.x & 63;
    if (node0 >= N) return;
    int node1 = node0 + 1;                      // N even
    const f32x4 pv = *reinterpret_cast<const f32x4*>(p + lane * 4);
    const f32x4 a = *reinterpret_cast<const f32x4*>(x + (size_t)node0 * 256 + lane * 4);
    const f32x4 b = *reinterpret_cast<const f32x4*>(x + (size_t)node1 * 256 + lane * 4);
    float acc0 = a.x * pv.x + a.y * pv.y + a.z * pv.z + a.w * pv.w;
    float acc1 = b.x * pv.x + b.y * pv.y + b.z * pv.z + b.w * pv.w;
    #pragma unroll
    for (int off = 32; off; off >>= 1) {
        acc0 += __shfl_down(acc0, off, 64);
        acc1 += __shfl_down(acc1, off, 64);
    }
    if (lane == 0) {
        s[node0] = acc0;
        s[node1] = acc1;
        int b0 = batch[node0];
        if (node0 == 0 || batch[node0 - 1] != b0) start[b0] = node0;
        int b1 = batch[node1];
        if (b0 != b1) start[b1] = node1;
    }
}

// Kernel 2: 65 blocks. Blocks 0..B-1: per-graph softmax stats (max, expsum).
// Block B: 64-lane prefix scan -> kk, Kb, Db, Ktot.
__global__ __launch_bounds__(256) void k2_meta_stats(
    const float* __restrict__ s, const int* __restrict__ start, int N, int B,
    int* __restrict__ kk, int* __restrict__ Kb, int* __restrict__ Db,
    int* __restrict__ Ktot, float* __restrict__ mx, float* __restrict__ denom) {
    if (blockIdx.x == (unsigned)B) {
        int g = threadIdx.x;
        if (g >= B) return;                 // wave 0 only (B==64)
        int st = start[g];
        int en = (g == B - 1) ? N : start[g + 1];
        int cnt = en - st;
        int kv = (int)ceilf(RATIO * (float)cnt);
        int dv = cnt - kv;
        int kp = kv, dp = dv;
        #pragma unroll
        for (int off = 1; off < 64; off <<= 1) {
            int a = __shfl_up(kp, off, 64);
            int b_ = __shfl_up(dp, off, 64);
            if (g >= off) { kp += a; dp += b_; }
        }
        kk[g] = kv;
        Kb[g] = kp - kv;
        Db[g] = dp - dv;
        if (g == B - 1) *Ktot = kp;
        return;
    }
    int g = blockIdx.x;
    int st = start[g];
    int en = (g == B - 1) ? N : start[g + 1];
    __shared__ float red[256];
    float m = -INFINITY;
    for (int i = st + threadIdx.x; i < en; i += 256) m = fmaxf(m, s[i]);
    red[threadIdx.x] = m; __syncthreads();
    for (int o = 128; o; o >>= 1) {
        if (threadIdx.x < o) red[threadIdx.x] = fmaxf(red[threadIdx.x], red[threadIdx.x + o]);
        __syncthreads();
    }
    m = red[0]; __syncthreads();
    float sum = 0.f;
    for (int i = st + threadIdx.x; i < en; i += 256) sum += expf(s[i] - m);
    red[threadIdx.x] = sum; __syncthreads();
    for (int o = 128; o; o >>= 1) {
        if (threadIdx.x < o) red[threadIdx.x] += red[threadIdx.x + o];
        __syncthreads();
    }
    if (threadIdx.x == 0) { mx[g] = m; denom[g] = red[0]; }
}

// Kernel 3: blocks [0, SB): gate + permute rows (2 rows/wave, normal x loads —
// L3-resident from k1 — and nt output stores). Blocks [SB, SB+EB): edge rewrite,
// 8 edges/thread. Block-uniform branch; no intra-block divergence.
// Stable argsort of new_batch => kept (g, idx) -> Kb[g]+idx; dropped ->
// Ktot + Db[g] + (idx - k[g]). new_batch_sorted[id]==B <=> id >= Ktot.
// senders_out = mask ? recv : send; receivers_out = recv (sequential overwrite).
__global__ __launch_bounds__(256) void k3_scatter_edges(
    const float* __restrict__ x, const float* __restrict__ s,
    const int* __restrict__ batch, const int* __restrict__ start,
    const int* __restrict__ kk, const int* __restrict__ Kb, const int* __restrict__ Db,
    const int* __restrict__ Ktot, const float* __restrict__ mx, const float* __restrict__ denom,
    const int* __restrict__ snd, const int* __restrict__ rcv,
    int N, int B, int E, int SB,
    float* __restrict__ xout, float* __restrict__ nbout,
    float* __restrict__ sout, float* __restrict__ rout) {
    if ((int)blockIdx.x < SB) {
        int node0 = blockIdx.x * 8 + (threadIdx.x >> 6) * 2;
        if (node0 >= N) return;
        int node1 = node0 + 1;
        int lane = threadIdx.x & 63;
        int kt = *Ktot;

        int g0 = batch[node0], g1 = batch[node1];
        int idx0 = node0 - start[g0], idx1 = node1 - start[g1];
        int kv0 = kk[g0], kv1 = kk[g1];
        bool kept0 = idx0 < kv0, kept1 = idx1 < kv1;
        int pos0 = kept0 ? (Kb[g0] + idx0) : (kt + Db[g0] + (idx0 - kv0));
        int pos1 = kept1 ? (Kb[g1] + idx1) : (kt + Db[g1] + (idx1 - kv1));
        float sc0 = expf(s[node0] - mx[g0]) / denom[g0];
        float sc1 = expf(s[node1] - mx[g1]) / denom[g1];

        const f32x4 a = *reinterpret_cast<const f32x4*>(x + (size_t)node0 * 256 + lane * 4);
        const f32x4 b = *reinterpret_cast<const f32x4*>(x + (size_t)node1 * 256 + lane * 4);
        f32x4 oa, ob;
        oa.x = a.x * sc0; oa.y = a.y * sc0; oa.z = a.z * sc0; oa.w = a.w * sc0;
        ob.x = b.x * sc1; ob.y = b.y * sc1; ob.z = b.z * sc1; ob.w = b.w * sc1;
        __builtin_nontemporal_store(oa, reinterpret_cast<f32x4*>(xout + (size_t)pos0 * 256 + lane * 4));
        __builtin_nontemporal_store(ob, reinterpret_cast<f32x4*>(xout + (size_t)pos1 * 256 + lane * 4));
        if (lane == 0) {
            __builtin_nontemporal_store((float)(kept0 ? g0 : B), nbout + pos0);
            __builtin_nontemporal_store((float)(kept1 ? g1 : B), nbout + pos1);
        }
    } else {
        int t = (blockIdx.x - SB) * blockDim.x + threadIdx.x;
        long base = (long)t * 8;
        if (base >= E) return;
        int kt = *Ktot;
        if (base + 8 <= E) {
            i32x4 s0 = __builtin_nontemporal_load(reinterpret_cast<const i32x4*>(snd + base));
            i32x4 s1 = __builtin_nontemporal_load(reinterpret_cast<const i32x4*>(snd + base + 4));
            i32x4 r0 = __builtin_nontemporal_load(reinterpret_cast<const i32x4*>(rcv + base));
            i32x4 r1 = __builtin_nontemporal_load(reinterpret_cast<const i32x4*>(rcv + base + 4));
            f32x4 so0, so1, ro0, ro1;
            so0.x = (float)(((s0.x >= kt) || (r0.x >= kt)) ? r0.x : s0.x);
            so0.y = (float)(((s0.y >= kt) || (r0.y >= kt)) ? r0.y : s0.y);
            so0.z = (float)(((s0.z >= kt) || (r0.z >= kt)) ? r0.z : s0.z);
            so0.w = (float)(((s0.w >= kt) || (r0.w >= kt)) ? r0.w : s0.w);
            so1.x = (float)(((s1.x >= kt) || (r1.x >= kt)) ? r1.x : s1.x);
            so1.y = (float)(((s1.y >= kt) || (r1.y >= kt)) ? r1.y : s1.y);
            so1.z = (float)(((s1.z >= kt) || (r1.z >= kt)) ? r1.z : s1.z);
            so1.w = (float)(((s1.w >= kt) || (r1.w >= kt)) ? r1.w : s1.w);
            ro0.x = (float)r0.x; ro0.y = (float)r0.y; ro0.z = (float)r0.z; ro0.w = (float)r0.w;
            ro1.x = (float)r1.x; ro1.y = (float)r1.y; ro1.z = (float)r1.z; ro1.w = (float)r1.w;
            __builtin_nontemporal_store(so0, reinterpret_cast<f32x4*>(sout + base));
            __builtin_nontemporal_store(so1, reinterpret_cast<f32x4*>(sout + base + 4));
            __builtin_nontemporal_store(ro0, reinterpret_cast<f32x4*>(rout + base));
            __builtin_nontemporal_store(ro1, reinterpret_cast<f32x4*>(rout + base + 4));
        } else {
            for (long e = base; e < E; ++e) {
                int sv = snd[e], rv = rcv[e];
                bool m = (sv >= kt) || (rv >= kt);
                sout[e] = (float)(m ? rv : sv);
                rout[e] = (float)rv;
            }
        }
    }
}

extern "C" void kernel_launch(void* const* d_in, const int* in_sizes, int n_in,
                              void* d_out, int out_size, void* d_ws, size_t ws_size,
                              hipStream_t stream) {
    const float* x = (const float*)d_in[0];
    const float* p = (const float*)d_in[1];
    const int* senders = (const int*)d_in[2];
    const int* receivers = (const int*)d_in[3];
    const int* batch = (const int*)d_in[4];

    const int C = in_sizes[1];   // 256
    const int E = in_sizes[2];   // 3,200,000
    const int N = in_sizes[4];   // 200,000
    const int B = 64;

    char* ws = (char*)d_ws;
    float* s   = (float*)ws;                       // N floats
    int* start = (int*)(ws + (size_t)N * 4);       // B ints
    int* kk    = start + B;
    int* Kb    = kk + B;
    int* Db    = Kb + B;
    int* Ktot  = Db + B;
    float* mx    = (float*)(Ktot + 1);
    float* denom = mx + B;

    float* out   = (float*)d_out;
    float* xout  = out;
    float* sout  = out + (size_t)N * C;
    float* rout  = sout + E;
    float* nbout = rout + E;

    int SB = (N + 7) / 8;                          // scatter blocks (25000)
    int EB = ((E + 7) / 8 + 255) / 256;            // edge blocks (1563)

    k1_scores_boundary<<<SB, 256, 0, stream>>>(x, p, batch, s, start, N);
    k2_meta_stats     <<<B + 1, 256, 0, stream>>>(s, start, N, B, kk, Kb, Db, Ktot, mx, denom);
    k3_scatter_edges  <<<SB + EB, 256, 0, stream>>>(x, s, batch, start, kk, Kb, Db, Ktot,
                                                    mx, denom, senders, receivers,
                                                    N, B, E, SB, xout, nbout, sout, rout);
}

// Round 11
// 113.699 us; speedup vs baseline: 2.8481x; 1.0038x over previous
//
#include <hip/hip_runtime.h>
#include <hip/hip_bf16.h>
#include <stdint.h>

// TopKPooling (haiku-geometric): N=200000, C=256, B=64, E=3.2M, RATIO=0.5
// Inputs (f32/int32): x [N,C] f32, p [C] f32, senders/receivers int32, batch int32 (sorted).
// Output d_out: FLOAT32, concatenated (x_out [N*C] | senders_out [E] | receivers_out [E]
// | new_batch_sorted [N]).
//
// R11 = R10 + ONE change: k3's scatter blocks process nodes in REVERSE order
// (block b -> node range of block SB-1-b). k1 streamed x forward, so L3/MALL
// holds the TAIL of x most-recently-used; reading tail-first chases the MRU
// wavefront instead of the evicted LRU end. Everything else identical to R10.

#define RATIO 0.5f

typedef float f32x4 __attribute__((ext_vector_type(4)));
typedef int   i32x4 __attribute__((ext_vector_type(4)));

// Kernel 1: scores (2 rows per wave, float4 per lane, C=256) + boundary detection.
__global__ __launch_bounds__(256) void k1_scores_boundary(
    const float* __restrict__ x, const float* __restrict__ p,
    const int* __restrict__ batch,
    float* __restrict__ s, int* __restrict__ start, int N) {
    int node0 = blockIdx.x * 8 + (threadIdx.x >> 6) * 2;
    int lane = threadIdx.x & 63;
    if (node0 >= N) return;
    int node1 = node0 + 1;                      // N even
    const f32x4 pv = *reinterpret_cast<const f32x4*>(p + lane * 4);
    const f32x4 a = *reinterpret_cast<const f32x4*>(x + (size_t)node0 * 256 + lane * 4);
    const f32x4 b = *reinterpret_cast<const f32x4*>(x + (size_t)node1 * 256 + lane * 4);
    float acc0 = a.x * pv.x + a.y * pv.y + a.z * pv.z + a.w * pv.w;
    float acc1 = b.x * pv.x + b.y * pv.y + b.z * pv.z + b.w * pv.w;
    #pragma unroll
    for (int off = 32; off; off >>= 1) {
        acc0 += __shfl_down(acc0, off, 64);
        acc1 += __shfl_down(acc1, off, 64);
    }
    if (lane == 0) {
        s[node0] = acc0;
        s[node1] = acc1;
        int b0 = batch[node0];
        if (node0 == 0 || batch[node0 - 1] != b0) start[b0] = node0;
        int b1 = batch[node1];
        if (b0 != b1) start[b1] = node1;
    }
}

// Kernel 2: 65 blocks. Blocks 0..B-1: per-graph softmax stats (max, expsum).
// Block B: 64-lane prefix scan -> kk, Kb, Db, Ktot.
__global__ __launch_bounds__(256) void k2_meta_stats(
    const float* __restrict__ s, const int* __restrict__ start, int N, int B,
    int* __restrict__ kk, int* __restrict__ Kb, int* __restrict__ Db,
    int* __restrict__ Ktot, float* __restrict__ mx, float* __restrict__ denom) {
    if (blockIdx.x == (unsigned)B) {
        int g = threadIdx.x;
        if (g >= B) return;                 // wave 0 only (B==64)
        int st = start[g];
        int en = (g == B - 1) ? N : start[g + 1];
        int cnt = en - st;
        int kv = (int)ceilf(RATIO * (float)cnt);
        int dv = cnt - kv;
        int kp = kv, dp = dv;
        #pragma unroll
        for (int off = 1; off < 64; off <<= 1) {
            int a = __shfl_up(kp, off, 64);
            int b_ = __shfl_up(dp, off, 64);
            if (g >= off) { kp += a; dp += b_; }
        }
        kk[g] = kv;
        Kb[g] = kp - kv;
        Db[g] = dp - dv;
        if (g == B - 1) *Ktot = kp;
        return;
    }
    int g = blockIdx.x;
    int st = start[g];
    int en = (g == B - 1) ? N : start[g + 1];
    __shared__ float red[256];
    float m = -INFINITY;
    for (int i = st + threadIdx.x; i < en; i += 256) m = fmaxf(m, s[i]);
    red[threadIdx.x] = m; __syncthreads();
    for (int o = 128; o; o >>= 1) {
        if (threadIdx.x < o) red[threadIdx.x] = fmaxf(red[threadIdx.x], red[threadIdx.x + o]);
        __syncthreads();
    }
    m = red[0]; __syncthreads();
    float sum = 0.f;
    for (int i = st + threadIdx.x; i < en; i += 256) sum += expf(s[i] - m);
    red[threadIdx.x] = sum; __syncthreads();
    for (int o = 128; o; o >>= 1) {
        if (threadIdx.x < o) red[threadIdx.x] += red[threadIdx.x + o];
        __syncthreads();
    }
    if (threadIdx.x == 0) { mx[g] = m; denom[g] = red[0]; }
}

// Kernel 3: blocks [0, SB): gate + permute rows, processed in REVERSE block order
// (MRU-first re-read of x). Blocks [SB, SB+EB): edge rewrite, 8 edges/thread.
// Block-uniform branch; no intra-block divergence.
// Stable argsort of new_batch => kept (g, idx) -> Kb[g]+idx; dropped ->
// Ktot + Db[g] + (idx - k[g]). new_batch_sorted[id]==B <=> id >= Ktot.
// senders_out = mask ? recv : send; receivers_out = recv (sequential overwrite).
__global__ __launch_bounds__(256) void k3_scatter_edges(
    const float* __restrict__ x, const float* __restrict__ s,
    const int* __restrict__ batch, const int* __restrict__ start,
    const int* __restrict__ kk, const int* __restrict__ Kb, const int* __restrict__ Db,
    const int* __restrict__ Ktot, const float* __restrict__ mx, const float* __restrict__ denom,
    const int* __restrict__ snd, const int* __restrict__ rcv,
    int N, int B, int E, int SB,
    float* __restrict__ xout, float* __restrict__ nbout,
    float* __restrict__ sout, float* __restrict__ rout) {
    if ((int)blockIdx.x < SB) {
        int rb = SB - 1 - (int)blockIdx.x;          // reversed block order
        int node0 = rb * 8 + (threadIdx.x >> 6) * 2;
        if (node0 >= N) return;
        int node1 = node0 + 1;
        int lane = threadIdx.x & 63;
        int kt = *Ktot;

        int g0 = batch[node0], g1 = batch[node1];
        int idx0 = node0 - start[g0], idx1 = node1 - start[g1];
        int kv0 = kk[g0], kv1 = kk[g1];
        bool kept0 = idx0 < kv0, kept1 = idx1 < kv1;
        int pos0 = kept0 ? (Kb[g0] + idx0) : (kt + Db[g0] + (idx0 - kv0));
        int pos1 = kept1 ? (Kb[g1] + idx1) : (kt + Db[g1] + (idx1 - kv1));
        float sc0 = expf(s[node0] - mx[g0]) / denom[g0];
        float sc1 = expf(s[node1] - mx[g1]) / denom[g1];

        const f32x4 a = *reinterpret_cast<const f32x4*>(x + (size_t)node0 * 256 + lane * 4);
        const f32x4 b = *reinterpret_cast<const f32x4*>(x + (size_t)node1 * 256 + lane * 4);
        f32x4 oa, ob;
        oa.x = a.x * sc0; oa.y = a.y * sc0; oa.z = a.z * sc0; oa.w = a.w * sc0;
        ob.x = b.x * sc1; ob.y = b.y * sc1; ob.z = b.z * sc1; ob.w = b.w * sc1;
        __builtin_nontemporal_store(oa, reinterpret_cast<f32x4*>(xout + (size_t)pos0 * 256 + lane * 4));
        __builtin_nontemporal_store(ob, reinterpret_cast<f32x4*>(xout + (size_t)pos1 * 256 + lane * 4));
        if (lane == 0) {
            __builtin_nontemporal_store((float)(kept0 ? g0 : B), nbout + pos0);
            __builtin_nontemporal_store((float)(kept1 ? g1 : B), nbout + pos1);
        }
    } else {
        int t = (blockIdx.x - SB) * blockDim.x + threadIdx.x;
        long base = (long)t * 8;
        if (base >= E) return;
        int kt = *Ktot;
        if (base + 8 <= E) {
            i32x4 s0 = __builtin_nontemporal_load(reinterpret_cast<const i32x4*>(snd + base));
            i32x4 s1 = __builtin_nontemporal_load(reinterpret_cast<const i32x4*>(snd + base + 4));
            i32x4 r0 = __builtin_nontemporal_load(reinterpret_cast<const i32x4*>(rcv + base));
            i32x4 r1 = __builtin_nontemporal_load(reinterpret_cast<const i32x4*>(rcv + base + 4));
            f32x4 so0, so1, ro0, ro1;
            so0.x = (float)(((s0.x >= kt) || (r0.x >= kt)) ? r0.x : s0.x);
            so0.y = (float)(((s0.y >= kt) || (r0.y >= kt)) ? r0.y : s0.y);
            so0.z = (float)(((s0.z >= kt) || (r0.z >= kt)) ? r0.z : s0.z);
            so0.w = (float)(((s0.w >= kt) || (r0.w >= kt)) ? r0.w : s0.w);
            so1.x = (float)(((s1.x >= kt) || (r1.x >= kt)) ? r1.x : s1.x);
            so1.y = (float)(((s1.y >= kt) || (r1.y >= kt)) ? r1.y : s1.y);
            so1.z = (float)(((s1.z >= kt) || (r1.z >= kt)) ? r1.z : s1.z);
            so1.w = (float)(((s1.w >= kt) || (r1.w >= kt)) ? r1.w : s1.w);
            ro0.x = (float)r0.x; ro0.y = (float)r0.y; ro0.z = (float)r0.z; ro0.w = (float)r0.w;
            ro1.x = (float)r1.x; ro1.y = (float)r1.y; ro1.z = (float)r1.z; ro1.w = (float)r1.w;
            __builtin_nontemporal_store(so0, reinterpret_cast<f32x4*>(sout + base));
            __builtin_nontemporal_store(so1, reinterpret_cast<f32x4*>(sout + base + 4));
            __builtin_nontemporal_store(ro0, reinterpret_cast<f32x4*>(rout + base));
            __builtin_nontemporal_store(ro1, reinterpret_cast<f32x4*>(rout + base + 4));
        } else {
            for (long e = base; e < E; ++e) {
                int sv = snd[e], rv = rcv[e];
                bool m = (sv >= kt) || (rv >= kt);
                sout[e] = (float)(m ? rv : sv);
                rout[e] = (float)rv;
            }
        }
    }
}

extern "C" void kernel_launch(void* const* d_in, const int* in_sizes, int n_in,
                              void* d_out, int out_size, void* d_ws, size_t ws_size,
                              hipStream_t stream) {
    const float* x = (const float*)d_in[0];
    const float* p = (const float*)d_in[1];
    const int* senders = (const int*)d_in[2];
    const int* receivers = (const int*)d_in[3];
    const int* batch = (const int*)d_in[4];

    const int C = in_sizes[1];   // 256
    const int E = in_sizes[2];   // 3,200,000
    const int N = in_sizes[4];   // 200,000
    const int B = 64;

    char* ws = (char*)d_ws;
    float* s   = (float*)ws;                       // N floats
    int* start = (int*)(ws + (size_t)N * 4);       // B ints
    int* kk    = start + B;
    int* Kb    = kk + B;
    int* Db    = Kb + B;
    int* Ktot  = Db + B;
    float* mx    = (float*)(Ktot + 1);
    float* denom = mx + B;

    float* out   = (float*)d_out;
    float* xout  = out;
    float* sout  = out + (size_t)N * C;
    float* rout  = sout + E;
    float* nbout = rout + E;

    int SB = (N + 7) / 8;                          // scatter blocks (25000)
    int EB = ((E + 7) / 8 + 255) / 256;            // edge blocks (1563)

    k1_scores_boundary<<<SB, 256, 0, stream>>>(x, p, batch, s, start, N);
    k2_meta_stats     <<<B + 1, 256, 0, stream>>>(s, start, N, B, kk, Kb, Db, Ktot, mx, denom);
    k3_scatter_edges  <<<SB + EB, 256, 0, stream>>>(x, s, batch, start, kk, Kb, Db, Ktot,
                                                    mx, denom, senders, receivers,
                                                    N, B, E, SB, xout, nbout, sout, rout);
}